// Round 21
// baseline (77.869 us; speedup 1.0000x reference)
//
#include <hip/hip_runtime.h>
#include <hip/hip_bf16.h>
#include <stdint.h>

typedef __bf16 bf16;
typedef __attribute__((ext_vector_type(8))) __bf16 bf16x8;
typedef __attribute__((ext_vector_type(2))) __bf16 bf16x2;
typedef __attribute__((ext_vector_type(4))) float f32x4;
typedef __attribute__((ext_vector_type(4))) unsigned int u32x4;

static constexpr int T_LEN = 4096;
static constexpr int WIN = 16;

__device__ __forceinline__ bf16x8 cvt8(float4 a, float4 b) {
  bf16x8 o;
  o[0] = (bf16)a.x; o[1] = (bf16)a.y; o[2] = (bf16)a.z; o[3] = (bf16)a.w;
  o[4] = (bf16)b.x; o[5] = (bf16)b.y; o[6] = (bf16)b.z; o[7] = (bf16)b.w;
  return o;
}

// ---- QKV GEMM: 128x64 tiles, 1536 blocks; A from fp32 x, B from fp32 W* ----
// (in-register cast -> ds_write_b128 into the swizzled BK=64 layout; no prep)
__global__ __launch_bounds__(256) void gemm_qkv_kernel(const float* __restrict__ Xf,
                                                       const float* __restrict__ Wq,
                                                       const float* __restrict__ Wk,
                                                       const float* __restrict__ Wv,
                                                       bf16* __restrict__ Cb) {
  constexpr int K = 512, BK = 64, NIT = K / BK;  // 8
  __shared__ __align__(16) bf16 As[8192];  // 128 rows x 64
  __shared__ __align__(16) bf16 Bs[4096];  // 64 rows x 64
  const int tid = threadIdx.x;
  const int l = tid & 63;
  const int w = tid >> 6;
  const int g = l >> 4;
  const int c = l & 15;
  int bid = blockIdx.x;
  bid = (bid & 7) * 192 + (bid >> 3);  // XCD swizzle (1536 = 8*192)
  const int m0 = (bid / 24) * 128;     // 64 M-tiles
  const int n0 = (bid % 24) * 64;      // 24 N-tiles
  const float* Bsrc = (n0 < 512) ? Wq : (n0 < 1024) ? Wk : Wv;
  const int nr0 = n0 & 511;

  const int wm = (w >> 1) * 64;
  const int wn = (w & 1) * 32;
  const int cx = c & 7;

  const f32x4 zero = {0.f, 0.f, 0.f, 0.f};
  f32x4 acc[4][2];
#pragma unroll
  for (int i = 0; i < 4; ++i)
#pragma unroll
    for (int j = 0; j < 2; ++j) acc[i][j] = zero;

#pragma unroll 1
  for (int t = 0; t < NIT; ++t) {
    const int k0 = t * BK;
#pragma unroll
    for (int i = 0; i < 4; ++i) {  // A: 128 rows x 8 chunks = 1024 slots
      int s = tid + i * 256;
      int row = s >> 3;
      int j = s & 7;
      int ksrc = k0 + ((j ^ (row & 7)) << 3);
      const float4* ap = (const float4*)(Xf + (size_t)(m0 + row) * 512 + ksrc);
      float4 a0 = ap[0], a1 = ap[1];
      *(bf16x8*)&As[s * 8] = cvt8(a0, a1);
    }
#pragma unroll
    for (int i = 0; i < 2; ++i) {  // B: 64 rows x 8 chunks = 512 slots
      int s = tid + i * 256;
      int row = s >> 3;
      int j = s & 7;
      int ksrc = k0 + ((j ^ (row & 7)) << 3);
      const float4* bp = (const float4*)(Bsrc + (size_t)(nr0 + row) * 512 + ksrc);
      float4 b0 = bp[0], b1 = bp[1];
      *(bf16x8*)&Bs[s * 8] = cvt8(b0, b1);
    }
    __syncthreads();
#pragma unroll
    for (int kk = 0; kk < 2; ++kk) {
      const int joff = ((kk * 4 + g) ^ cx) << 3;
      bf16x8 af[4], bfr[2];
#pragma unroll
      for (int mi = 0; mi < 4; ++mi)
        af[mi] = *(const bf16x8*)&As[(wm + mi * 16 + c) * 64 + joff];
#pragma unroll
      for (int ni = 0; ni < 2; ++ni)
        bfr[ni] = *(const bf16x8*)&Bs[(wn + ni * 16 + c) * 64 + joff];
#pragma unroll
      for (int mi = 0; mi < 4; ++mi)
#pragma unroll
        for (int ni = 0; ni < 2; ++ni)
          acc[mi][ni] = __builtin_amdgcn_mfma_f32_16x16x32_bf16(af[mi], bfr[ni], acc[mi][ni], 0, 0, 0);
    }
    __syncthreads();
  }

  // ---- C epilogue: wave-private LDS bounce (64x32, 4KB/wave in As) ----
  bf16* Cw = &As[w * 2048];
  const int r0 = (l >> 4) * 4;
#pragma unroll
  for (int mi = 0; mi < 4; ++mi)
#pragma unroll
    for (int ni = 0; ni < 2; ++ni)
#pragma unroll
      for (int r = 0; r < 4; ++r)
        Cw[(mi * 16 + r0 + r) * 32 + ni * 16 + c] = (bf16)acc[mi][ni][r];
#pragma unroll
  for (int i = 0; i < 4; ++i) {
    int row = (l >> 2) + 16 * i;
    bf16x8 v = *(const bf16x8*)&Cw[row * 32 + (l & 3) * 8];
    *(bf16x8*)(Cb + (size_t)(m0 + wm + row) * 1536 + n0 + wn + (l & 3) * 8) = v;
  }
}

// ---- FUSED attn + proj + residual + LayerNorm (R17-exact structure) ----
// Only change: proj B prefetch loads fp32 Wp and casts in-register (wpb gone).
__global__ __launch_bounds__(512) void attn_proj_ln_kernel(
    const bf16* __restrict__ qkv, const float* __restrict__ Wp,
    const float* __restrict__ X, const float* __restrict__ gamma,
    const float* __restrict__ beta, float* __restrict__ out) {
  __shared__ __align__(16) bf16 POOL[63744];  // 127,488 B
  bf16* KV = POOL;
  bf16* Pp = POOL + 36864;
  bf16* aoutL = POOL + 46080;
  float* rsum = (float*)(POOL + 62720);
  float* rsq  = (float*)(POOL + 63232);

  const int tid = threadIdx.x;
  const int w = tid >> 6;
  const int l = tid & 63;
  const int g = l >> 4;
  const int c = l & 15;
  const int cx = c & 7;
  int bid = blockIdx.x;
  bid = (bid & 7) * 32 + (bid >> 3);  // XCD swizzle: 256 = 8*32
  const int m0 = bid * 32;
  const int b = m0 >> 12;
  const int tloc0 = m0 & (T_LEN - 1);
  const int base = b * T_LEN;

  const f32x4 zero = {0.f, 0.f, 0.f, 0.f};
  const u32x4 zu = {0u, 0u, 0u, 0u};
  const float scale = 0.125f;

  // ---- one-time zero of Vt pad cols 64..71 for all 4 head-slots x 64 rows ----
  if (tid < 256) {
    int hl = tid >> 6;
    int row = tid & 63;
    *(uint4*)&KV[18432 + hl * 4608 + row * 72 + 64] = make_uint4(0u, 0u, 0u, 0u);
  }

  // ================= attention phase =================
#pragma unroll 1
  for (int pass = 0; pass < 2; ++pass) {
    if (pass) __syncthreads();
#pragma unroll
    for (int i = 0; i < 4; ++i) {
      int task = tid + i * 512;
      int hl = task >> 9;
      int rem = task & 511;
      int pp = rem >> 3;
      int c8 = (rem & 7) * 8;
      int h = pass * 4 + hl;
      int pg = base + min(max(tloc0 - WIN + pp, 0), T_LEN - 1);
      const bf16* kr = qkv + (size_t)pg * 1536 + 512 + h * 64 + c8;
      const bf16* vr = qkv + (size_t)pg * 1536 + 1024 + h * 64 + c8;
      *(bf16x8*)&KV[hl * 4608 + pp * 72 + c8] = *(const bf16x8*)kr;
      bf16x8 vv = *(const bf16x8*)vr;
      bf16* vt = &KV[18432 + hl * 4608];
#pragma unroll
      for (int e = 0; e < 8; ++e)
        vt[(c8 + e) * 72 + pp] = vv[e];
    }
    __syncthreads();

    const int hl = w >> 1;
    const int wh = w & 1;
    const int h = pass * 4 + hl;
    const int tg = tloc0 + wh * 16;
    bf16* Kl = &KV[hl * 4608];
    bf16* Vt = &KV[18432 + hl * 4608];

    const bf16* qrow = qkv + (size_t)(base + tg + c) * 1536 + h * 64;
    bf16x8 qf0 = *(const bf16x8*)(qrow + g * 8);
    bf16x8 qf1 = *(const bf16x8*)(qrow + 32 + g * 8);

    f32x4 st[3];
#pragma unroll
    for (int wt = 0; wt < 3; ++wt) {
      int rk = 16 * wh + 16 * wt + c;
      bf16x8 ka0 = *(const bf16x8*)&Kl[rk * 72 + g * 8];
      bf16x8 ka1 = *(const bf16x8*)&Kl[rk * 72 + 32 + g * 8];
      f32x4 t = __builtin_amdgcn_mfma_f32_16x16x32_bf16(ka0, qf0, zero, 0, 0, 0);
      st[wt] = __builtin_amdgcn_mfma_f32_16x16x32_bf16(ka1, qf1, t, 0, 0, 0);
    }

    float pv[3][4];
    float lsum = 0.f;
#pragma unroll
    for (int wt = 0; wt < 3; ++wt)
#pragma unroll
      for (int r = 0; r < 4; ++r) {
        int ww = 16 * wt + 4 * g + r;
        int pos = tg - WIN + ww;
        bool valid = (ww >= c) && (ww <= c + 32) && (pos >= 0) && (pos < T_LEN);
        float e = __expf(st[wt][r] * scale);
        pv[wt][r] = valid ? e : 0.f;
        lsum += pv[wt][r];
      }
    lsum += __shfl_xor(lsum, 16);
    lsum += __shfl_xor(lsum, 32);
    float inv = 1.f / lsum;

    bf16* P = &Pp[w * 1152];
#pragma unroll
    for (int wt = 0; wt < 3; ++wt) {
      bf16x2 p01, p23;
      p01[0] = (bf16)(pv[wt][0] * inv);
      p01[1] = (bf16)(pv[wt][1] * inv);
      p23[0] = (bf16)(pv[wt][2] * inv);
      p23[1] = (bf16)(pv[wt][3] * inv);
      *(bf16x2*)&P[c * 56 + 16 * wt + 4 * g]     = p01;
      *(bf16x2*)&P[c * 56 + 16 * wt + 4 * g + 2] = p23;
    }

    bf16x8 pa0 = *(const bf16x8*)&P[c * 56 + 8 * g];
    int g1 = (g < 2) ? g : 1;
    bf16x8 pa1 = *(const bf16x8*)&P[c * 56 + 32 + 8 * g1];
    if (g >= 2) pa1 = __builtin_bit_cast(bf16x8, zu);

    const int off0 = 16 * wh + 8 * g;
    const int off1 = 16 * wh + ((g < 2) ? 32 + 8 * g : 48);
    f32x4 acc[4] = {zero, zero, zero, zero};
#pragma unroll
    for (int dt = 0; dt < 4; ++dt) {
      bf16x8 v0 = *(const bf16x8*)&Vt[(16 * dt + c) * 72 + off0];
      bf16x8 v1 = *(const bf16x8*)&Vt[(16 * dt + c) * 72 + off1];
      acc[dt] = __builtin_amdgcn_mfma_f32_16x16x32_bf16(pa0, v0, acc[dt], 0, 0, 0);
      acc[dt] = __builtin_amdgcn_mfma_f32_16x16x32_bf16(pa1, v1, acc[dt], 0, 0, 0);
    }

#pragma unroll
    for (int dt = 0; dt < 4; ++dt)
#pragma unroll
      for (int r = 0; r < 4; ++r)
        aoutL[(wh * 16 + 4 * g + r) * 520 + h * 64 + 16 * dt + c] = (bf16)acc[dt][r];
  }

  // ---- issue proj tile-0 B loads (fp32 Wp -> reg-cast), overlaps barrier ----
  bf16x8 breg[8];
#pragma unroll
  for (int i = 0; i < 8; ++i) {
    int s = tid + i * 512;
    int row = s >> 3;
    int j = s & 7;
    const float4* bp = (const float4*)(Wp + (size_t)row * 512 + ((j ^ (row & 7)) << 3));
    breg[i] = cvt8(bp[0], bp[1]);
  }
  __syncthreads();  // aout complete; KV region free for B staging

  // ================= proj + residual + LN phase =================
  f32x4 acc2[2][4];
#pragma unroll
  for (int m = 0; m < 2; ++m)
#pragma unroll
    for (int n = 0; n < 4; ++n) acc2[m][n] = zero;

#pragma unroll 1
  for (int t = 0; t < 8; ++t) {
    const int k0 = t * 64;
#pragma unroll
    for (int i = 0; i < 8; ++i) {
      int s = tid + i * 512;
      *(bf16x8*)&KV[s * 8] = breg[i];
    }
    __syncthreads();  // tile t visible to all waves
    if (t < 7) {
      const int k1 = k0 + 64;
#pragma unroll
      for (int i = 0; i < 8; ++i) {
        int s = tid + i * 512;
        int row = s >> 3;
        int j = s & 7;
        const float4* bp =
            (const float4*)(Wp + (size_t)row * 512 + k1 + ((j ^ (row & 7)) << 3));
        breg[i] = cvt8(bp[0], bp[1]);
      }
    }
#pragma unroll
    for (int kk = 0; kk < 2; ++kk) {
      const int joff = ((kk * 4 + g) ^ cx) << 3;
      bf16x8 af[2], bfv[4];
#pragma unroll
      for (int m = 0; m < 2; ++m)
        af[m] = *(const bf16x8*)&aoutL[(m * 16 + c) * 520 + k0 + (kk * 4 + g) * 8];
#pragma unroll
      for (int n = 0; n < 4; ++n)
        bfv[n] = *(const bf16x8*)&KV[(w * 64 + n * 16 + c) * 64 + joff];
#pragma unroll
      for (int m = 0; m < 2; ++m)
#pragma unroll
        for (int n = 0; n < 4; ++n)
          acc2[m][n] = __builtin_amdgcn_mfma_f32_16x16x32_bf16(af[m], bfv[n], acc2[m][n], 0, 0, 0);
    }
    __syncthreads();  // all reads of tile t done before next ds_write
  }

  const int col0 = w * 64 + c;
  float ps[2][4], ps2[2][4];
#pragma unroll
  for (int m = 0; m < 2; ++m)
#pragma unroll
    for (int r = 0; r < 4; ++r) {
      int row = m0 + m * 16 + 4 * g + r;
      float s = 0.f, s2 = 0.f;
#pragma unroll
      for (int n = 0; n < 4; ++n) {
        float y = acc2[m][n][r] + X[(size_t)row * 512 + col0 + n * 16];
        acc2[m][n][r] = y;
        s += y;
        s2 += y * y;
      }
      ps[m][r] = s;
      ps2[m][r] = s2;
    }
#pragma unroll
  for (int m = 0; m < 2; ++m)
#pragma unroll
    for (int r = 0; r < 4; ++r) {
      float s = ps[m][r], s2 = ps2[m][r];
      s += __shfl_xor(s, 1);  s2 += __shfl_xor(s2, 1);
      s += __shfl_xor(s, 2);  s2 += __shfl_xor(s2, 2);
      s += __shfl_xor(s, 4);  s2 += __shfl_xor(s2, 4);
      s += __shfl_xor(s, 8);  s2 += __shfl_xor(s2, 8);
      ps[m][r] = s;
      ps2[m][r] = s2;
    }
  if (c == 0) {
#pragma unroll
    for (int m = 0; m < 2; ++m)
#pragma unroll
      for (int r = 0; r < 4; ++r) {
        rsum[(m * 16 + 4 * g + r) * 8 + w] = ps[m][r];
        rsq[(m * 16 + 4 * g + r) * 8 + w] = ps2[m][r];
      }
  }
  __syncthreads();

  float gam[4], bet[4];
#pragma unroll
  for (int n = 0; n < 4; ++n) {
    gam[n] = gamma[col0 + n * 16];
    bet[n] = beta[col0 + n * 16];
  }
#pragma unroll
  for (int m = 0; m < 2; ++m)
#pragma unroll
    for (int r = 0; r < 4; ++r) {
      int rl = m * 16 + 4 * g + r;
      float sum = 0.f, sq = 0.f;
#pragma unroll
      for (int j = 0; j < 8; ++j) {
        sum += rsum[rl * 8 + j];
        sq += rsq[rl * 8 + j];
      }
      float mu = sum * (1.f / 512.f);
      float var = sq * (1.f / 512.f) - mu * mu;
      float rs = rsqrtf(var + 1e-5f);
#pragma unroll
      for (int n = 0; n < 4; ++n)
        out[(size_t)(m0 + rl) * 512 + col0 + n * 16] =
            gam[n] * (acc2[m][n][r] - mu) * rs + bet[n];
    }
}

extern "C" void kernel_launch(void* const* d_in, const int* in_sizes, int n_in,
                              void* d_out, int out_size, void* d_ws, size_t ws_size,
                              hipStream_t stream) {
  const float* x  = (const float*)d_in[0];
  const float* Wq = (const float*)d_in[1];
  const float* Wk = (const float*)d_in[2];
  const float* Wv = (const float*)d_in[3];
  const float* Wp = (const float*)d_in[4];
  const float* g  = (const float*)d_in[5];
  const float* be = (const float*)d_in[6];
  float* out = (float*)d_out;

  bf16* qkv = (bf16*)d_ws;  // 25,165,824 B

  // QKV: M=8192 (64 tiles of 128), N=1536 (24 tiles of 64) -> 1536 blocks
  gemm_qkv_kernel<<<1536, 256, 0, stream>>>(x, Wq, Wk, Wv, qkv);
  // fused attn + proj + residual + LN: 8192/32 = 256 blocks
  attn_proj_ln_kernel<<<256, 512, 0, stream>>>(qkv, Wp, x, g, be, out);
}

// Round 22
// 62.901 us; speedup vs baseline: 1.2380x; 1.2380x over previous
//
#include <hip/hip_runtime.h>
#include <hip/hip_bf16.h>
#include <stdint.h>

typedef __bf16 bf16;
typedef __attribute__((ext_vector_type(8))) __bf16 bf16x8;
typedef __attribute__((ext_vector_type(2))) __bf16 bf16x2;
typedef __attribute__((ext_vector_type(4))) float f32x4;
typedef __attribute__((ext_vector_type(4))) unsigned int u32x4;

#define GLOAD16(gsrc, ldst)                                              \
  __builtin_amdgcn_global_load_lds(                                      \
      (const __attribute__((address_space(1))) unsigned int*)(gsrc),     \
      (__attribute__((address_space(3))) unsigned int*)(ldst), 16, 0, 0)

static constexpr int T_LEN = 4096;
static constexpr int WIN = 16;

__device__ __forceinline__ bf16x8 cvt8(float4 a, float4 b) {
  bf16x8 o;
  o[0] = (bf16)a.x; o[1] = (bf16)a.y; o[2] = (bf16)a.z; o[3] = (bf16)a.w;
  o[4] = (bf16)b.x; o[5] = (bf16)b.y; o[6] = (bf16)b.z; o[7] = (bf16)b.w;
  return o;
}

// ---- casts: blocks 0..2047 -> x, 2048..2431 -> Wq/Wk/Wv (Wp not needed) ----
__global__ __launch_bounds__(256) void prep_kernel(const float* __restrict__ x,
                                                   const float* __restrict__ wq,
                                                   const float* __restrict__ wk,
                                                   const float* __restrict__ wv,
                                                   bf16* __restrict__ xb,
                                                   bf16* __restrict__ wqkv) {
  int bid = blockIdx.x;
  if (bid < 2048) {
    int i = bid * 256 + threadIdx.x;
    const float4* s4 = (const float4*)x + (size_t)i * 2;
    ((bf16x8*)xb)[i] = cvt8(s4[0], s4[1]);
  } else {
    int i = (bid - 2048) * 256 + threadIdx.x;  // 98304 threads = 3 * 32768
    int which = i >> 15;
    int j = i & 32767;
    const float* src = (which == 0) ? wq : (which == 1) ? wk : wv;
    bf16* dst = wqkv + (size_t)which * 512 * 512;
    const float4* s4 = (const float4*)src + (size_t)j * 2;
    ((bf16x8*)dst)[j] = cvt8(s4[0], s4[1]);
  }
}

// ---- QKV GEMM (R17-exact): bf16 global_load_lds, 128x64 tiles, 1536 blocks ----
__global__ __launch_bounds__(256) void gemm_qkv_kernel(const bf16* __restrict__ Ab,
                                                       const bf16* __restrict__ Bw,
                                                       bf16* __restrict__ Cb) {
  constexpr int K = 512, BK = 64, NIT = K / BK;  // 8
  __shared__ __align__(16) bf16 As[8192];  // 128 rows x 64
  __shared__ __align__(16) bf16 Bs[4096];  // 64 rows x 64
  const int tid = threadIdx.x;
  const int l = tid & 63;
  const int w = tid >> 6;
  const int g = l >> 4;
  const int c = l & 15;
  int bid = blockIdx.x;
  bid = (bid & 7) * 192 + (bid >> 3);  // XCD swizzle (1536 = 8*192)
  const int m0 = (bid / 24) * 128;     // 64 M-tiles
  const int n0 = (bid % 24) * 64;      // 24 N-tiles

  const int wm = (w >> 1) * 64;
  const int wn = (w & 1) * 32;
  const int cx = c & 7;

  const f32x4 zero = {0.f, 0.f, 0.f, 0.f};
  f32x4 acc[4][2];
#pragma unroll
  for (int i = 0; i < 4; ++i)
#pragma unroll
    for (int j = 0; j < 2; ++j) acc[i][j] = zero;

#pragma unroll 1
  for (int t = 0; t < NIT; ++t) {
    const int k0 = t * BK;
#pragma unroll
    for (int i = 0; i < 4; ++i) {  // A: 128 rows x 8 chunks = 1024 slots
      int s = tid + i * 256;
      int row = s >> 3;
      int j = s & 7;
      GLOAD16(Ab + (size_t)(m0 + row) * 512 + k0 + ((j ^ (row & 7)) << 3),
              &As[s * 8]);
    }
#pragma unroll
    for (int i = 0; i < 2; ++i) {  // B: 64 rows x 8 chunks = 512 slots
      int s = tid + i * 256;
      int row = s >> 3;
      int j = s & 7;
      GLOAD16(Bw + (size_t)(n0 + row) * 512 + k0 + ((j ^ (row & 7)) << 3),
              &Bs[s * 8]);
    }
    __syncthreads();
#pragma unroll
    for (int kk = 0; kk < 2; ++kk) {
      const int joff = ((kk * 4 + g) ^ cx) << 3;
      bf16x8 af[4], bfr[2];
#pragma unroll
      for (int mi = 0; mi < 4; ++mi)
        af[mi] = *(const bf16x8*)&As[(wm + mi * 16 + c) * 64 + joff];
#pragma unroll
      for (int ni = 0; ni < 2; ++ni)
        bfr[ni] = *(const bf16x8*)&Bs[(wn + ni * 16 + c) * 64 + joff];
#pragma unroll
      for (int mi = 0; mi < 4; ++mi)
#pragma unroll
        for (int ni = 0; ni < 2; ++ni)
          acc[mi][ni] = __builtin_amdgcn_mfma_f32_16x16x32_bf16(af[mi], bfr[ni], acc[mi][ni], 0, 0, 0);
    }
    __syncthreads();
  }

  // ---- C epilogue: wave-private LDS bounce (64x32, 4KB/wave in As) ----
  bf16* Cw = &As[w * 2048];
  const int r0 = (l >> 4) * 4;
#pragma unroll
  for (int mi = 0; mi < 4; ++mi)
#pragma unroll
    for (int ni = 0; ni < 2; ++ni)
#pragma unroll
      for (int r = 0; r < 4; ++r)
        Cw[(mi * 16 + r0 + r) * 32 + ni * 16 + c] = (bf16)acc[mi][ni][r];
#pragma unroll
  for (int i = 0; i < 4; ++i) {
    int row = (l >> 2) + 16 * i;
    bf16x8 v = *(const bf16x8*)&Cw[row * 32 + (l & 3) * 8];
    *(bf16x8*)(Cb + (size_t)(m0 + wm + row) * 1536 + n0 + wn + (l & 3) * 8) = v;
  }
}

// ---- FUSED attn + proj + residual + LayerNorm (R21 version, passed) ----
__global__ __launch_bounds__(512) void attn_proj_ln_kernel(
    const bf16* __restrict__ qkv, const float* __restrict__ Wp,
    const float* __restrict__ X, const float* __restrict__ gamma,
    const float* __restrict__ beta, float* __restrict__ out) {
  __shared__ __align__(16) bf16 POOL[63744];  // 127,488 B
  bf16* KV = POOL;
  bf16* Pp = POOL + 36864;
  bf16* aoutL = POOL + 46080;
  float* rsum = (float*)(POOL + 62720);
  float* rsq  = (float*)(POOL + 63232);

  const int tid = threadIdx.x;
  const int w = tid >> 6;
  const int l = tid & 63;
  const int g = l >> 4;
  const int c = l & 15;
  const int cx = c & 7;
  int bid = blockIdx.x;
  bid = (bid & 7) * 32 + (bid >> 3);  // XCD swizzle: 256 = 8*32
  const int m0 = bid * 32;
  const int b = m0 >> 12;
  const int tloc0 = m0 & (T_LEN - 1);
  const int base = b * T_LEN;

  const f32x4 zero = {0.f, 0.f, 0.f, 0.f};
  const u32x4 zu = {0u, 0u, 0u, 0u};
  const float scale = 0.125f;

  // ---- one-time zero of Vt pad cols 64..71 for all 4 head-slots x 64 rows ----
  if (tid < 256) {
    int hl = tid >> 6;
    int row = tid & 63;
    *(uint4*)&KV[18432 + hl * 4608 + row * 72 + 64] = make_uint4(0u, 0u, 0u, 0u);
  }

  // ================= attention phase =================
#pragma unroll 1
  for (int pass = 0; pass < 2; ++pass) {
    if (pass) __syncthreads();
#pragma unroll
    for (int i = 0; i < 4; ++i) {
      int task = tid + i * 512;
      int hl = task >> 9;
      int rem = task & 511;
      int pp = rem >> 3;
      int c8 = (rem & 7) * 8;
      int h = pass * 4 + hl;
      int pg = base + min(max(tloc0 - WIN + pp, 0), T_LEN - 1);
      const bf16* kr = qkv + (size_t)pg * 1536 + 512 + h * 64 + c8;
      const bf16* vr = qkv + (size_t)pg * 1536 + 1024 + h * 64 + c8;
      *(bf16x8*)&KV[hl * 4608 + pp * 72 + c8] = *(const bf16x8*)kr;
      bf16x8 vv = *(const bf16x8*)vr;
      bf16* vt = &KV[18432 + hl * 4608];
#pragma unroll
      for (int e = 0; e < 8; ++e)
        vt[(c8 + e) * 72 + pp] = vv[e];
    }
    __syncthreads();

    const int hl = w >> 1;
    const int wh = w & 1;
    const int h = pass * 4 + hl;
    const int tg = tloc0 + wh * 16;
    bf16* Kl = &KV[hl * 4608];
    bf16* Vt = &KV[18432 + hl * 4608];

    const bf16* qrow = qkv + (size_t)(base + tg + c) * 1536 + h * 64;
    bf16x8 qf0 = *(const bf16x8*)(qrow + g * 8);
    bf16x8 qf1 = *(const bf16x8*)(qrow + 32 + g * 8);

    f32x4 st[3];
#pragma unroll
    for (int wt = 0; wt < 3; ++wt) {
      int rk = 16 * wh + 16 * wt + c;
      bf16x8 ka0 = *(const bf16x8*)&Kl[rk * 72 + g * 8];
      bf16x8 ka1 = *(const bf16x8*)&Kl[rk * 72 + 32 + g * 8];
      f32x4 t = __builtin_amdgcn_mfma_f32_16x16x32_bf16(ka0, qf0, zero, 0, 0, 0);
      st[wt] = __builtin_amdgcn_mfma_f32_16x16x32_bf16(ka1, qf1, t, 0, 0, 0);
    }

    float pv[3][4];
    float lsum = 0.f;
#pragma unroll
    for (int wt = 0; wt < 3; ++wt)
#pragma unroll
      for (int r = 0; r < 4; ++r) {
        int ww = 16 * wt + 4 * g + r;
        int pos = tg - WIN + ww;
        bool valid = (ww >= c) && (ww <= c + 32) && (pos >= 0) && (pos < T_LEN);
        float e = __expf(st[wt][r] * scale);
        pv[wt][r] = valid ? e : 0.f;
        lsum += pv[wt][r];
      }
    lsum += __shfl_xor(lsum, 16);
    lsum += __shfl_xor(lsum, 32);
    float inv = 1.f / lsum;

    bf16* P = &Pp[w * 1152];
#pragma unroll
    for (int wt = 0; wt < 3; ++wt) {
      bf16x2 p01, p23;
      p01[0] = (bf16)(pv[wt][0] * inv);
      p01[1] = (bf16)(pv[wt][1] * inv);
      p23[0] = (bf16)(pv[wt][2] * inv);
      p23[1] = (bf16)(pv[wt][3] * inv);
      *(bf16x2*)&P[c * 56 + 16 * wt + 4 * g]     = p01;
      *(bf16x2*)&P[c * 56 + 16 * wt + 4 * g + 2] = p23;
    }

    bf16x8 pa0 = *(const bf16x8*)&P[c * 56 + 8 * g];
    int g1 = (g < 2) ? g : 1;
    bf16x8 pa1 = *(const bf16x8*)&P[c * 56 + 32 + 8 * g1];
    if (g >= 2) pa1 = __builtin_bit_cast(bf16x8, zu);

    const int off0 = 16 * wh + 8 * g;
    const int off1 = 16 * wh + ((g < 2) ? 32 + 8 * g : 48);
    f32x4 acc[4] = {zero, zero, zero, zero};
#pragma unroll
    for (int dt = 0; dt < 4; ++dt) {
      bf16x8 v0 = *(const bf16x8*)&Vt[(16 * dt + c) * 72 + off0];
      bf16x8 v1 = *(const bf16x8*)&Vt[(16 * dt + c) * 72 + off1];
      acc[dt] = __builtin_amdgcn_mfma_f32_16x16x32_bf16(pa0, v0, acc[dt], 0, 0, 0);
      acc[dt] = __builtin_amdgcn_mfma_f32_16x16x32_bf16(pa1, v1, acc[dt], 0, 0, 0);
    }

#pragma unroll
    for (int dt = 0; dt < 4; ++dt)
#pragma unroll
      for (int r = 0; r < 4; ++r)
        aoutL[(wh * 16 + 4 * g + r) * 520 + h * 64 + 16 * dt + c] = (bf16)acc[dt][r];
  }

  // ---- issue proj tile-0 B loads (fp32 Wp -> reg-cast), overlaps barrier ----
  bf16x8 breg[8];
#pragma unroll
  for (int i = 0; i < 8; ++i) {
    int s = tid + i * 512;
    int row = s >> 3;
    int j = s & 7;
    const float4* bp = (const float4*)(Wp + (size_t)row * 512 + ((j ^ (row & 7)) << 3));
    breg[i] = cvt8(bp[0], bp[1]);
  }
  __syncthreads();  // aout complete; KV region free for B staging

  // ================= proj + residual + LN phase =================
  f32x4 acc2[2][4];
#pragma unroll
  for (int m = 0; m < 2; ++m)
#pragma unroll
    for (int n = 0; n < 4; ++n) acc2[m][n] = zero;

#pragma unroll 1
  for (int t = 0; t < 8; ++t) {
    const int k0 = t * 64;
#pragma unroll
    for (int i = 0; i < 8; ++i) {
      int s = tid + i * 512;
      *(bf16x8*)&KV[s * 8] = breg[i];
    }
    __syncthreads();  // tile t visible to all waves
    if (t < 7) {
      const int k1 = k0 + 64;
#pragma unroll
      for (int i = 0; i < 8; ++i) {
        int s = tid + i * 512;
        int row = s >> 3;
        int j = s & 7;
        const float4* bp =
            (const float4*)(Wp + (size_t)row * 512 + k1 + ((j ^ (row & 7)) << 3));
        breg[i] = cvt8(bp[0], bp[1]);
      }
    }
#pragma unroll
    for (int kk = 0; kk < 2; ++kk) {
      const int joff = ((kk * 4 + g) ^ cx) << 3;
      bf16x8 af[2], bfv[4];
#pragma unroll
      for (int m = 0; m < 2; ++m)
        af[m] = *(const bf16x8*)&aoutL[(m * 16 + c) * 520 + k0 + (kk * 4 + g) * 8];
#pragma unroll
      for (int n = 0; n < 4; ++n)
        bfv[n] = *(const bf16x8*)&KV[(w * 64 + n * 16 + c) * 64 + joff];
#pragma unroll
      for (int m = 0; m < 2; ++m)
#pragma unroll
        for (int n = 0; n < 4; ++n)
          acc2[m][n] = __builtin_amdgcn_mfma_f32_16x16x32_bf16(af[m], bfv[n], acc2[m][n], 0, 0, 0);
    }
    __syncthreads();  // all reads of tile t done before next ds_write
  }

  const int col0 = w * 64 + c;
  float ps[2][4], ps2[2][4];
#pragma unroll
  for (int m = 0; m < 2; ++m)
#pragma unroll
    for (int r = 0; r < 4; ++r) {
      int row = m0 + m * 16 + 4 * g + r;
      float s = 0.f, s2 = 0.f;
#pragma unroll
      for (int n = 0; n < 4; ++n) {
        float y = acc2[m][n][r] + X[(size_t)row * 512 + col0 + n * 16];
        acc2[m][n][r] = y;
        s += y;
        s2 += y * y;
      }
      ps[m][r] = s;
      ps2[m][r] = s2;
    }
#pragma unroll
  for (int m = 0; m < 2; ++m)
#pragma unroll
    for (int r = 0; r < 4; ++r) {
      float s = ps[m][r], s2 = ps2[m][r];
      s += __shfl_xor(s, 1);  s2 += __shfl_xor(s2, 1);
      s += __shfl_xor(s, 2);  s2 += __shfl_xor(s2, 2);
      s += __shfl_xor(s, 4);  s2 += __shfl_xor(s2, 4);
      s += __shfl_xor(s, 8);  s2 += __shfl_xor(s2, 8);
      ps[m][r] = s;
      ps2[m][r] = s2;
    }
  if (c == 0) {
#pragma unroll
    for (int m = 0; m < 2; ++m)
#pragma unroll
      for (int r = 0; r < 4; ++r) {
        rsum[(m * 16 + 4 * g + r) * 8 + w] = ps[m][r];
        rsq[(m * 16 + 4 * g + r) * 8 + w] = ps2[m][r];
      }
  }
  __syncthreads();

  float gam[4], bet[4];
#pragma unroll
  for (int n = 0; n < 4; ++n) {
    gam[n] = gamma[col0 + n * 16];
    bet[n] = beta[col0 + n * 16];
  }
#pragma unroll
  for (int m = 0; m < 2; ++m)
#pragma unroll
    for (int r = 0; r < 4; ++r) {
      int rl = m * 16 + 4 * g + r;
      float sum = 0.f, sq = 0.f;
#pragma unroll
      for (int j = 0; j < 8; ++j) {
        sum += rsum[rl * 8 + j];
        sq += rsq[rl * 8 + j];
      }
      float mu = sum * (1.f / 512.f);
      float var = sq * (1.f / 512.f) - mu * mu;
      float rs = rsqrtf(var + 1e-5f);
#pragma unroll
      for (int n = 0; n < 4; ++n)
        out[(size_t)(m0 + rl) * 512 + col0 + n * 16] =
            gam[n] * (acc2[m][n][r] - mu) * rs + bet[n];
    }
}

extern "C" void kernel_launch(void* const* d_in, const int* in_sizes, int n_in,
                              void* d_out, int out_size, void* d_ws, size_t ws_size,
                              hipStream_t stream) {
  const float* x  = (const float*)d_in[0];
  const float* Wq = (const float*)d_in[1];
  const float* Wk = (const float*)d_in[2];
  const float* Wv = (const float*)d_in[3];
  const float* Wp = (const float*)d_in[4];
  const float* g  = (const float*)d_in[5];
  const float* be = (const float*)d_in[6];
  float* out = (float*)d_out;

  char* ws = (char*)d_ws;
  bf16* xb   = (bf16*)(ws);                          // 8,388,608 B
  bf16* wqkv = (bf16*)(ws + 8388608);                // 1,572,864 B
  bf16* qkv  = (bf16*)(ws + 9961472);                // 25,165,824 B

  prep_kernel<<<2432, 256, 0, stream>>>(x, Wq, Wk, Wv, xb, wqkv);
  // QKV: M=8192 (64 tiles of 128), N=1536 (24 tiles of 64) -> 1536 blocks
  gemm_qkv_kernel<<<1536, 256, 0, stream>>>(xb, wqkv, qkv);
  // fused attn + proj + residual + LN: 8192/32 = 256 blocks
  attn_proj_ln_kernel<<<256, 512, 0, stream>>>(qkv, Wp, x, g, be, out);
}

// Round 23
// 55.318 us; speedup vs baseline: 1.4077x; 1.1371x over previous
//
#include <hip/hip_runtime.h>
#include <hip/hip_bf16.h>
#include <stdint.h>

typedef __bf16 bf16;
typedef __attribute__((ext_vector_type(8))) __bf16 bf16x8;
typedef __attribute__((ext_vector_type(2))) __bf16 bf16x2;
typedef __attribute__((ext_vector_type(4))) float f32x4;
typedef __attribute__((ext_vector_type(4))) unsigned int u32x4;

#define GLOAD16(gsrc, ldst)                                              \
  __builtin_amdgcn_global_load_lds(                                      \
      (const __attribute__((address_space(1))) unsigned int*)(gsrc),     \
      (__attribute__((address_space(3))) unsigned int*)(ldst), 16, 0, 0)

static constexpr int T_LEN = 4096;
static constexpr int WIN = 16;

__device__ __forceinline__ bf16x8 cvt8(float4 a, float4 b) {
  bf16x8 o;
  o[0] = (bf16)a.x; o[1] = (bf16)a.y; o[2] = (bf16)a.z; o[3] = (bf16)a.w;
  o[4] = (bf16)b.x; o[5] = (bf16)b.y; o[6] = (bf16)b.z; o[7] = (bf16)b.w;
  return o;
}

// ---- fused casts: blocks 0..2047 -> x, 2048..2559 -> weights ----
__global__ __launch_bounds__(256) void prep_kernel(const float* __restrict__ x,
                                                   const float* __restrict__ wq,
                                                   const float* __restrict__ wk,
                                                   const float* __restrict__ wv,
                                                   const float* __restrict__ wp,
                                                   bf16* __restrict__ xb,
                                                   bf16* __restrict__ wqkv,
                                                   bf16* __restrict__ wpb) {
  int bid = blockIdx.x;
  if (bid < 2048) {
    int i = bid * 256 + threadIdx.x;
    const float4* s4 = (const float4*)x + (size_t)i * 2;
    ((bf16x8*)xb)[i] = cvt8(s4[0], s4[1]);
  } else {
    int i = (bid - 2048) * 256 + threadIdx.x;
    int which = i >> 15;
    int j = i & 32767;
    const float* src = (which == 0) ? wq : (which == 1) ? wk : (which == 2) ? wv : wp;
    bf16* dst = (which < 3) ? (wqkv + (size_t)which * 512 * 512) : wpb;
    const float4* s4 = (const float4*)src + (size_t)j * 2;
    ((bf16x8*)dst)[j] = cvt8(s4[0], s4[1]);
  }
}

// ---- QKV GEMM: single-buffer 2-barrier loop, 128x64 tiles -> 1536 blocks ----
__global__ __launch_bounds__(256) void gemm_qkv_kernel(const bf16* __restrict__ Ab,
                                                       const bf16* __restrict__ Bw,
                                                       bf16* __restrict__ Cb) {
  constexpr int K = 512, BK = 64, NIT = K / BK;  // 8
  __shared__ __align__(16) bf16 As[8192];  // 128 rows x 64
  __shared__ __align__(16) bf16 Bs[4096];  // 64 rows x 64
  const int tid = threadIdx.x;
  const int l = tid & 63;
  const int w = tid >> 6;
  const int g = l >> 4;
  const int c = l & 15;
  int bid = blockIdx.x;
  bid = (bid & 7) * 192 + (bid >> 3);  // XCD swizzle (1536 = 8*192)
  const int m0 = (bid / 24) * 128;     // 64 M-tiles
  const int n0 = (bid % 24) * 64;      // 24 N-tiles

  const int wm = (w >> 1) * 64;
  const int wn = (w & 1) * 32;
  const int cx = c & 7;

  const f32x4 zero = {0.f, 0.f, 0.f, 0.f};
  f32x4 acc[4][2];
#pragma unroll
  for (int i = 0; i < 4; ++i)
#pragma unroll
    for (int j = 0; j < 2; ++j) acc[i][j] = zero;

#pragma unroll 1
  for (int t = 0; t < NIT; ++t) {
    const int k0 = t * BK;
#pragma unroll
    for (int i = 0; i < 4; ++i) {  // A: 128 rows x 8 chunks = 1024 slots
      int s = tid + i * 256;
      int row = s >> 3;
      int j = s & 7;
      GLOAD16(Ab + (size_t)(m0 + row) * 512 + k0 + ((j ^ (row & 7)) << 3),
              &As[s * 8]);
    }
#pragma unroll
    for (int i = 0; i < 2; ++i) {  // B: 64 rows x 8 chunks = 512 slots
      int s = tid + i * 256;
      int row = s >> 3;
      int j = s & 7;
      GLOAD16(Bw + (size_t)(n0 + row) * 512 + k0 + ((j ^ (row & 7)) << 3),
              &Bs[s * 8]);
    }
    __syncthreads();
#pragma unroll
    for (int kk = 0; kk < 2; ++kk) {
      const int joff = ((kk * 4 + g) ^ cx) << 3;
      bf16x8 af[4], bfr[2];
#pragma unroll
      for (int mi = 0; mi < 4; ++mi)
        af[mi] = *(const bf16x8*)&As[(wm + mi * 16 + c) * 64 + joff];
#pragma unroll
      for (int ni = 0; ni < 2; ++ni)
        bfr[ni] = *(const bf16x8*)&Bs[(wn + ni * 16 + c) * 64 + joff];
#pragma unroll
      for (int mi = 0; mi < 4; ++mi)
#pragma unroll
        for (int ni = 0; ni < 2; ++ni)
          acc[mi][ni] = __builtin_amdgcn_mfma_f32_16x16x32_bf16(af[mi], bfr[ni], acc[mi][ni], 0, 0, 0);
    }
    __syncthreads();
  }

  // ---- C epilogue: wave-private LDS bounce (64x32, 4KB/wave in As) ----
  bf16* Cw = &As[w * 2048];
  const int r0 = (l >> 4) * 4;
#pragma unroll
  for (int mi = 0; mi < 4; ++mi)
#pragma unroll
    for (int ni = 0; ni < 2; ++ni)
#pragma unroll
      for (int r = 0; r < 4; ++r)
        Cw[(mi * 16 + r0 + r) * 32 + ni * 16 + c] = (bf16)acc[mi][ni][r];
#pragma unroll
  for (int i = 0; i < 4; ++i) {
    int row = (l >> 2) + 16 * i;
    bf16x8 v = *(const bf16x8*)&Cw[row * 32 + (l & 3) * 8];
    *(bf16x8*)(Cb + (size_t)(m0 + wm + row) * 1536 + n0 + wn + (l & 3) * 8) = v;
  }
}

// ---- FUSED attn + proj + residual + LayerNorm (R17-exact, best measured) ----
__global__ __launch_bounds__(512) void attn_proj_ln_kernel(
    const bf16* __restrict__ qkv, const bf16* __restrict__ Bw,
    const float* __restrict__ X, const float* __restrict__ gamma,
    const float* __restrict__ beta, float* __restrict__ out) {
  __shared__ __align__(16) bf16 POOL[63744];  // 127,488 B
  bf16* KV = POOL;
  bf16* Pp = POOL + 36864;
  bf16* aoutL = POOL + 46080;
  float* rsum = (float*)(POOL + 62720);
  float* rsq  = (float*)(POOL + 63232);

  const int tid = threadIdx.x;
  const int w = tid >> 6;
  const int l = tid & 63;
  const int g = l >> 4;
  const int c = l & 15;
  const int cx = c & 7;
  int bid = blockIdx.x;
  bid = (bid & 7) * 32 + (bid >> 3);  // XCD swizzle: 256 = 8*32
  const int m0 = bid * 32;
  const int b = m0 >> 12;
  const int tloc0 = m0 & (T_LEN - 1);
  const int base = b * T_LEN;

  const f32x4 zero = {0.f, 0.f, 0.f, 0.f};
  const u32x4 zu = {0u, 0u, 0u, 0u};
  const float scale = 0.125f;

  // ---- one-time zero of Vt pad cols 64..71 for all 4 head-slots x 64 rows ----
  if (tid < 256) {
    int hl = tid >> 6;
    int row = tid & 63;
    *(uint4*)&KV[18432 + hl * 4608 + row * 72 + 64] = make_uint4(0u, 0u, 0u, 0u);
  }

  // ================= attention phase =================
#pragma unroll 1
  for (int pass = 0; pass < 2; ++pass) {
    if (pass) __syncthreads();
#pragma unroll
    for (int i = 0; i < 4; ++i) {
      int task = tid + i * 512;
      int hl = task >> 9;
      int rem = task & 511;
      int pp = rem >> 3;
      int c8 = (rem & 7) * 8;
      int h = pass * 4 + hl;
      int pg = base + min(max(tloc0 - WIN + pp, 0), T_LEN - 1);
      const bf16* kr = qkv + (size_t)pg * 1536 + 512 + h * 64 + c8;
      const bf16* vr = qkv + (size_t)pg * 1536 + 1024 + h * 64 + c8;
      *(bf16x8*)&KV[hl * 4608 + pp * 72 + c8] = *(const bf16x8*)kr;
      bf16x8 vv = *(const bf16x8*)vr;
      bf16* vt = &KV[18432 + hl * 4608];
#pragma unroll
      for (int e = 0; e < 8; ++e)
        vt[(c8 + e) * 72 + pp] = vv[e];
    }
    __syncthreads();

    const int hl = w >> 1;
    const int wh = w & 1;
    const int h = pass * 4 + hl;
    const int tg = tloc0 + wh * 16;
    bf16* Kl = &KV[hl * 4608];
    bf16* Vt = &KV[18432 + hl * 4608];

    const bf16* qrow = qkv + (size_t)(base + tg + c) * 1536 + h * 64;
    bf16x8 qf0 = *(const bf16x8*)(qrow + g * 8);
    bf16x8 qf1 = *(const bf16x8*)(qrow + 32 + g * 8);

    f32x4 st[3];
#pragma unroll
    for (int wt = 0; wt < 3; ++wt) {
      int rk = 16 * wh + 16 * wt + c;
      bf16x8 ka0 = *(const bf16x8*)&Kl[rk * 72 + g * 8];
      bf16x8 ka1 = *(const bf16x8*)&Kl[rk * 72 + 32 + g * 8];
      f32x4 t = __builtin_amdgcn_mfma_f32_16x16x32_bf16(ka0, qf0, zero, 0, 0, 0);
      st[wt] = __builtin_amdgcn_mfma_f32_16x16x32_bf16(ka1, qf1, t, 0, 0, 0);
    }

    float pv[3][4];
    float lsum = 0.f;
#pragma unroll
    for (int wt = 0; wt < 3; ++wt)
#pragma unroll
      for (int r = 0; r < 4; ++r) {
        int ww = 16 * wt + 4 * g + r;
        int pos = tg - WIN + ww;
        bool valid = (ww >= c) && (ww <= c + 32) && (pos >= 0) && (pos < T_LEN);
        float e = __expf(st[wt][r] * scale);
        pv[wt][r] = valid ? e : 0.f;
        lsum += pv[wt][r];
      }
    lsum += __shfl_xor(lsum, 16);
    lsum += __shfl_xor(lsum, 32);
    float inv = 1.f / lsum;

    bf16* P = &Pp[w * 1152];
#pragma unroll
    for (int wt = 0; wt < 3; ++wt) {
      bf16x2 p01, p23;
      p01[0] = (bf16)(pv[wt][0] * inv);
      p01[1] = (bf16)(pv[wt][1] * inv);
      p23[0] = (bf16)(pv[wt][2] * inv);
      p23[1] = (bf16)(pv[wt][3] * inv);
      *(bf16x2*)&P[c * 56 + 16 * wt + 4 * g]     = p01;
      *(bf16x2*)&P[c * 56 + 16 * wt + 4 * g + 2] = p23;
    }

    bf16x8 pa0 = *(const bf16x8*)&P[c * 56 + 8 * g];
    int g1 = (g < 2) ? g : 1;
    bf16x8 pa1 = *(const bf16x8*)&P[c * 56 + 32 + 8 * g1];
    if (g >= 2) pa1 = __builtin_bit_cast(bf16x8, zu);

    const int off0 = 16 * wh + 8 * g;
    const int off1 = 16 * wh + ((g < 2) ? 32 + 8 * g : 48);
    f32x4 acc[4] = {zero, zero, zero, zero};
#pragma unroll
    for (int dt = 0; dt < 4; ++dt) {
      bf16x8 v0 = *(const bf16x8*)&Vt[(16 * dt + c) * 72 + off0];
      bf16x8 v1 = *(const bf16x8*)&Vt[(16 * dt + c) * 72 + off1];
      acc[dt] = __builtin_amdgcn_mfma_f32_16x16x32_bf16(pa0, v0, acc[dt], 0, 0, 0);
      acc[dt] = __builtin_amdgcn_mfma_f32_16x16x32_bf16(pa1, v1, acc[dt], 0, 0, 0);
    }

#pragma unroll
    for (int dt = 0; dt < 4; ++dt)
#pragma unroll
      for (int r = 0; r < 4; ++r)
        aoutL[(wh * 16 + 4 * g + r) * 520 + h * 64 + 16 * dt + c] = (bf16)acc[dt][r];
  }

  // ---- issue proj tile-0 B loads to REGS (overlaps attn tail + barrier) ----
  bf16x8 breg[8];
#pragma unroll
  for (int i = 0; i < 8; ++i) {
    int s = tid + i * 512;
    int row = s >> 3;
    int j = s & 7;
    breg[i] = *(const bf16x8*)(Bw + (size_t)row * 512 + ((j ^ (row & 7)) << 3));
  }
  __syncthreads();  // aout complete; KV region free for B staging

  // ================= proj + residual + LN phase =================
  f32x4 acc2[2][4];
#pragma unroll
  for (int m = 0; m < 2; ++m)
#pragma unroll
    for (int n = 0; n < 4; ++n) acc2[m][n] = zero;

#pragma unroll 1
  for (int t = 0; t < 8; ++t) {
    const int k0 = t * 64;
#pragma unroll
    for (int i = 0; i < 8; ++i) {
      int s = tid + i * 512;
      *(bf16x8*)&KV[s * 8] = breg[i];
    }
    __syncthreads();  // tile t visible to all waves
    if (t < 7) {
      const int k1 = k0 + 64;
#pragma unroll
      for (int i = 0; i < 8; ++i) {
        int s = tid + i * 512;
        int row = s >> 3;
        int j = s & 7;
        breg[i] = *(const bf16x8*)(Bw + (size_t)row * 512 + k1 + ((j ^ (row & 7)) << 3));
      }
    }
#pragma unroll
    for (int kk = 0; kk < 2; ++kk) {
      const int joff = ((kk * 4 + g) ^ cx) << 3;
      bf16x8 af[2], bfv[4];
#pragma unroll
      for (int m = 0; m < 2; ++m)
        af[m] = *(const bf16x8*)&aoutL[(m * 16 + c) * 520 + k0 + (kk * 4 + g) * 8];
#pragma unroll
      for (int n = 0; n < 4; ++n)
        bfv[n] = *(const bf16x8*)&KV[(w * 64 + n * 16 + c) * 64 + joff];
#pragma unroll
      for (int m = 0; m < 2; ++m)
#pragma unroll
        for (int n = 0; n < 4; ++n)
          acc2[m][n] = __builtin_amdgcn_mfma_f32_16x16x32_bf16(af[m], bfv[n], acc2[m][n], 0, 0, 0);
    }
    __syncthreads();  // all reads of tile t done before next ds_write
  }

  const int col0 = w * 64 + c;
  float ps[2][4], ps2[2][4];
#pragma unroll
  for (int m = 0; m < 2; ++m)
#pragma unroll
    for (int r = 0; r < 4; ++r) {
      int row = m0 + m * 16 + 4 * g + r;
      float s = 0.f, s2 = 0.f;
#pragma unroll
      for (int n = 0; n < 4; ++n) {
        float y = acc2[m][n][r] + X[(size_t)row * 512 + col0 + n * 16];
        acc2[m][n][r] = y;
        s += y;
        s2 += y * y;
      }
      ps[m][r] = s;
      ps2[m][r] = s2;
    }
#pragma unroll
  for (int m = 0; m < 2; ++m)
#pragma unroll
    for (int r = 0; r < 4; ++r) {
      float s = ps[m][r], s2 = ps2[m][r];
      s += __shfl_xor(s, 1);  s2 += __shfl_xor(s2, 1);
      s += __shfl_xor(s, 2);  s2 += __shfl_xor(s2, 2);
      s += __shfl_xor(s, 4);  s2 += __shfl_xor(s2, 4);
      s += __shfl_xor(s, 8);  s2 += __shfl_xor(s2, 8);
      ps[m][r] = s;
      ps2[m][r] = s2;
    }
  if (c == 0) {
#pragma unroll
    for (int m = 0; m < 2; ++m)
#pragma unroll
      for (int r = 0; r < 4; ++r) {
        rsum[(m * 16 + 4 * g + r) * 8 + w] = ps[m][r];
        rsq[(m * 16 + 4 * g + r) * 8 + w] = ps2[m][r];
      }
  }
  __syncthreads();

  float gam[4], bet[4];
#pragma unroll
  for (int n = 0; n < 4; ++n) {
    gam[n] = gamma[col0 + n * 16];
    bet[n] = beta[col0 + n * 16];
  }
#pragma unroll
  for (int m = 0; m < 2; ++m)
#pragma unroll
    for (int r = 0; r < 4; ++r) {
      int rl = m * 16 + 4 * g + r;
      float sum = 0.f, sq = 0.f;
#pragma unroll
      for (int j = 0; j < 8; ++j) {
        sum += rsum[rl * 8 + j];
        sq += rsq[rl * 8 + j];
      }
      float mu = sum * (1.f / 512.f);
      float var = sq * (1.f / 512.f) - mu * mu;
      float rs = rsqrtf(var + 1e-5f);
#pragma unroll
      for (int n = 0; n < 4; ++n)
        out[(size_t)(m0 + rl) * 512 + col0 + n * 16] =
            gam[n] * (acc2[m][n][r] - mu) * rs + bet[n];
    }
}

extern "C" void kernel_launch(void* const* d_in, const int* in_sizes, int n_in,
                              void* d_out, int out_size, void* d_ws, size_t ws_size,
                              hipStream_t stream) {
  const float* x  = (const float*)d_in[0];
  const float* Wq = (const float*)d_in[1];
  const float* Wk = (const float*)d_in[2];
  const float* Wv = (const float*)d_in[3];
  const float* Wp = (const float*)d_in[4];
  const float* g  = (const float*)d_in[5];
  const float* be = (const float*)d_in[6];
  float* out = (float*)d_out;

  char* ws = (char*)d_ws;
  bf16* xb   = (bf16*)(ws);                          // 8,388,608 B
  bf16* wqkv = (bf16*)(ws + 8388608);                // 1,572,864 B
  bf16* wpb  = (bf16*)(ws + 9961472);                //   524,288 B
  bf16* qkv  = (bf16*)(ws + 10485760);               // 25,165,824 B

  prep_kernel<<<2560, 256, 0, stream>>>(x, Wq, Wk, Wv, Wp, xb, wqkv, wpb);
  // QKV: M=8192 (64 tiles of 128), N=1536 (24 tiles of 64) -> 1536 blocks
  gemm_qkv_kernel<<<1536, 256, 0, stream>>>(xb, wqkv, qkv);
  // fused attn + proj + residual + LN: 8192/32 = 256 blocks
  attn_proj_ln_kernel<<<256, 512, 0, stream>>>(qkv, wpb, x, g, be, out);
}

// Round 24
// 50.714 us; speedup vs baseline: 1.5355x; 1.0908x over previous
//
#include <hip/hip_runtime.h>
#include <hip/hip_bf16.h>
#include <stdint.h>

typedef __bf16 bf16;
typedef __attribute__((ext_vector_type(8))) __bf16 bf16x8;
typedef __attribute__((ext_vector_type(2))) __bf16 bf16x2;
typedef __attribute__((ext_vector_type(4))) float f32x4;
typedef __attribute__((ext_vector_type(4))) unsigned int u32x4;

#define GLOAD16(gsrc, ldst)                                              \
  __builtin_amdgcn_global_load_lds(                                      \
      (const __attribute__((address_space(1))) unsigned int*)(gsrc),     \
      (__attribute__((address_space(3))) unsigned int*)(ldst), 16, 0, 0)

static constexpr int T_LEN = 4096;
static constexpr int WIN = 16;

__device__ __forceinline__ bf16x8 cvt8(float4 a, float4 b) {
  bf16x8 o;
  o[0] = (bf16)a.x; o[1] = (bf16)a.y; o[2] = (bf16)a.z; o[3] = (bf16)a.w;
  o[4] = (bf16)b.x; o[5] = (bf16)b.y; o[6] = (bf16)b.z; o[7] = (bf16)b.w;
  return o;
}

// ---- fused casts: blocks 0..2047 -> x, 2048..2559 -> weights ----
// Wp (which==3) is written CHUNK-MAJOR: Bp[chunk=k/8][row][8] so the proj
// B-fragment read is coalesced straight from global (no LDS staging needed).
__global__ __launch_bounds__(256) void prep_kernel(const float* __restrict__ x,
                                                   const float* __restrict__ wq,
                                                   const float* __restrict__ wk,
                                                   const float* __restrict__ wv,
                                                   const float* __restrict__ wp,
                                                   bf16* __restrict__ xb,
                                                   bf16* __restrict__ wqkv,
                                                   bf16* __restrict__ wpb) {
  int bid = blockIdx.x;
  if (bid < 2048) {
    int i = bid * 256 + threadIdx.x;
    const float4* s4 = (const float4*)x + (size_t)i * 2;
    ((bf16x8*)xb)[i] = cvt8(s4[0], s4[1]);
  } else {
    int i = (bid - 2048) * 256 + threadIdx.x;
    int which = i >> 15;
    int j = i & 32767;
    if (which < 3) {
      const float* src = (which == 0) ? wq : (which == 1) ? wk : wv;
      bf16* dst = wqkv + (size_t)which * 512 * 512;
      const float4* s4 = (const float4*)src + (size_t)j * 2;
      ((bf16x8*)dst)[j] = cvt8(s4[0], s4[1]);
    } else {
      // dst group j: chunk = j>>9, row = j&511; src = wp[row][chunk*8..+8)
      int chunk = j >> 9;
      int row = j & 511;
      const float4* s4 = (const float4*)(wp + (size_t)row * 512 + chunk * 8);
      ((bf16x8*)wpb)[j] = cvt8(s4[0], s4[1]);  // coalesced write
    }
  }
}

// ---- QKV GEMM: single-buffer 2-barrier loop, 128x64 tiles -> 1536 blocks ----
__global__ __launch_bounds__(256) void gemm_qkv_kernel(const bf16* __restrict__ Ab,
                                                       const bf16* __restrict__ Bw,
                                                       bf16* __restrict__ Cb) {
  constexpr int K = 512, BK = 64, NIT = K / BK;  // 8
  __shared__ __align__(16) bf16 As[8192];  // 128 rows x 64
  __shared__ __align__(16) bf16 Bs[4096];  // 64 rows x 64
  const int tid = threadIdx.x;
  const int l = tid & 63;
  const int w = tid >> 6;
  const int g = l >> 4;
  const int c = l & 15;
  int bid = blockIdx.x;
  bid = (bid & 7) * 192 + (bid >> 3);  // XCD swizzle (1536 = 8*192)
  const int m0 = (bid / 24) * 128;     // 64 M-tiles
  const int n0 = (bid % 24) * 64;      // 24 N-tiles

  const int wm = (w >> 1) * 64;
  const int wn = (w & 1) * 32;
  const int cx = c & 7;

  const f32x4 zero = {0.f, 0.f, 0.f, 0.f};
  f32x4 acc[4][2];
#pragma unroll
  for (int i = 0; i < 4; ++i)
#pragma unroll
    for (int j = 0; j < 2; ++j) acc[i][j] = zero;

#pragma unroll 1
  for (int t = 0; t < NIT; ++t) {
    const int k0 = t * BK;
#pragma unroll
    for (int i = 0; i < 4; ++i) {  // A: 128 rows x 8 chunks = 1024 slots
      int s = tid + i * 256;
      int row = s >> 3;
      int j = s & 7;
      GLOAD16(Ab + (size_t)(m0 + row) * 512 + k0 + ((j ^ (row & 7)) << 3),
              &As[s * 8]);
    }
#pragma unroll
    for (int i = 0; i < 2; ++i) {  // B: 64 rows x 8 chunks = 512 slots
      int s = tid + i * 256;
      int row = s >> 3;
      int j = s & 7;
      GLOAD16(Bw + (size_t)(n0 + row) * 512 + k0 + ((j ^ (row & 7)) << 3),
              &Bs[s * 8]);
    }
    __syncthreads();
#pragma unroll
    for (int kk = 0; kk < 2; ++kk) {
      const int joff = ((kk * 4 + g) ^ cx) << 3;
      bf16x8 af[4], bfr[2];
#pragma unroll
      for (int mi = 0; mi < 4; ++mi)
        af[mi] = *(const bf16x8*)&As[(wm + mi * 16 + c) * 64 + joff];
#pragma unroll
      for (int ni = 0; ni < 2; ++ni)
        bfr[ni] = *(const bf16x8*)&Bs[(wn + ni * 16 + c) * 64 + joff];
#pragma unroll
      for (int mi = 0; mi < 4; ++mi)
#pragma unroll
        for (int ni = 0; ni < 2; ++ni)
          acc[mi][ni] = __builtin_amdgcn_mfma_f32_16x16x32_bf16(af[mi], bfr[ni], acc[mi][ni], 0, 0, 0);
    }
    __syncthreads();
  }

  // ---- C epilogue: wave-private LDS bounce (64x32, 4KB/wave in As) ----
  bf16* Cw = &As[w * 2048];
  const int r0 = (l >> 4) * 4;
#pragma unroll
  for (int mi = 0; mi < 4; ++mi)
#pragma unroll
    for (int ni = 0; ni < 2; ++ni)
#pragma unroll
      for (int r = 0; r < 4; ++r)
        Cw[(mi * 16 + r0 + r) * 32 + ni * 16 + c] = (bf16)acc[mi][ni][r];
#pragma unroll
  for (int i = 0; i < 4; ++i) {
    int row = (l >> 2) + 16 * i;
    bf16x8 v = *(const bf16x8*)&Cw[row * 32 + (l & 3) * 8];
    *(bf16x8*)(Cb + (size_t)(m0 + wm + row) * 1536 + n0 + wn + (l & 3) * 8) = v;
  }
}

// ---- FUSED attn + proj + residual + LayerNorm ----
// attn phase = R17-exact. Proj phase: B read DIRECTLY from chunk-major Bp
// (coalesced 256B runs per 16-lane group) -> no LDS staging, ZERO barriers.
__global__ __launch_bounds__(512) void attn_proj_ln_kernel(
    const bf16* __restrict__ qkv, const bf16* __restrict__ Bp,
    const float* __restrict__ X, const float* __restrict__ gamma,
    const float* __restrict__ beta, float* __restrict__ out) {
  __shared__ __align__(16) bf16 POOL[63744];  // 127,488 B
  bf16* KV = POOL;
  bf16* Pp = POOL + 36864;
  bf16* aoutL = POOL + 46080;
  float* rsum = (float*)(POOL + 62720);
  float* rsq  = (float*)(POOL + 63232);

  const int tid = threadIdx.x;
  const int w = tid >> 6;
  const int l = tid & 63;
  const int g = l >> 4;
  const int c = l & 15;
  int bid = blockIdx.x;
  bid = (bid & 7) * 32 + (bid >> 3);  // XCD swizzle: 256 = 8*32
  const int m0 = bid * 32;
  const int b = m0 >> 12;
  const int tloc0 = m0 & (T_LEN - 1);
  const int base = b * T_LEN;

  const f32x4 zero = {0.f, 0.f, 0.f, 0.f};
  const u32x4 zu = {0u, 0u, 0u, 0u};
  const float scale = 0.125f;

  // ---- one-time zero of Vt pad cols 64..71 for all 4 head-slots x 64 rows ----
  if (tid < 256) {
    int hl = tid >> 6;
    int row = tid & 63;
    *(uint4*)&KV[18432 + hl * 4608 + row * 72 + 64] = make_uint4(0u, 0u, 0u, 0u);
  }

  // ================= attention phase =================
#pragma unroll 1
  for (int pass = 0; pass < 2; ++pass) {
    if (pass) __syncthreads();
#pragma unroll
    for (int i = 0; i < 4; ++i) {
      int task = tid + i * 512;
      int hl = task >> 9;
      int rem = task & 511;
      int pp = rem >> 3;
      int c8 = (rem & 7) * 8;
      int h = pass * 4 + hl;
      int pg = base + min(max(tloc0 - WIN + pp, 0), T_LEN - 1);
      const bf16* kr = qkv + (size_t)pg * 1536 + 512 + h * 64 + c8;
      const bf16* vr = qkv + (size_t)pg * 1536 + 1024 + h * 64 + c8;
      *(bf16x8*)&KV[hl * 4608 + pp * 72 + c8] = *(const bf16x8*)kr;
      bf16x8 vv = *(const bf16x8*)vr;
      bf16* vt = &KV[18432 + hl * 4608];
#pragma unroll
      for (int e = 0; e < 8; ++e)
        vt[(c8 + e) * 72 + pp] = vv[e];
    }
    __syncthreads();

    const int hl = w >> 1;
    const int wh = w & 1;
    const int h = pass * 4 + hl;
    const int tg = tloc0 + wh * 16;
    bf16* Kl = &KV[hl * 4608];
    bf16* Vt = &KV[18432 + hl * 4608];

    const bf16* qrow = qkv + (size_t)(base + tg + c) * 1536 + h * 64;
    bf16x8 qf0 = *(const bf16x8*)(qrow + g * 8);
    bf16x8 qf1 = *(const bf16x8*)(qrow + 32 + g * 8);

    f32x4 st[3];
#pragma unroll
    for (int wt = 0; wt < 3; ++wt) {
      int rk = 16 * wh + 16 * wt + c;
      bf16x8 ka0 = *(const bf16x8*)&Kl[rk * 72 + g * 8];
      bf16x8 ka1 = *(const bf16x8*)&Kl[rk * 72 + 32 + g * 8];
      f32x4 t = __builtin_amdgcn_mfma_f32_16x16x32_bf16(ka0, qf0, zero, 0, 0, 0);
      st[wt] = __builtin_amdgcn_mfma_f32_16x16x32_bf16(ka1, qf1, t, 0, 0, 0);
    }

    float pv[3][4];
    float lsum = 0.f;
#pragma unroll
    for (int wt = 0; wt < 3; ++wt)
#pragma unroll
      for (int r = 0; r < 4; ++r) {
        int ww = 16 * wt + 4 * g + r;
        int pos = tg - WIN + ww;
        bool valid = (ww >= c) && (ww <= c + 32) && (pos >= 0) && (pos < T_LEN);
        float e = __expf(st[wt][r] * scale);
        pv[wt][r] = valid ? e : 0.f;
        lsum += pv[wt][r];
      }
    lsum += __shfl_xor(lsum, 16);
    lsum += __shfl_xor(lsum, 32);
    float inv = 1.f / lsum;

    bf16* P = &Pp[w * 1152];
#pragma unroll
    for (int wt = 0; wt < 3; ++wt) {
      bf16x2 p01, p23;
      p01[0] = (bf16)(pv[wt][0] * inv);
      p01[1] = (bf16)(pv[wt][1] * inv);
      p23[0] = (bf16)(pv[wt][2] * inv);
      p23[1] = (bf16)(pv[wt][3] * inv);
      *(bf16x2*)&P[c * 56 + 16 * wt + 4 * g]     = p01;
      *(bf16x2*)&P[c * 56 + 16 * wt + 4 * g + 2] = p23;
    }

    bf16x8 pa0 = *(const bf16x8*)&P[c * 56 + 8 * g];
    int g1 = (g < 2) ? g : 1;
    bf16x8 pa1 = *(const bf16x8*)&P[c * 56 + 32 + 8 * g1];
    if (g >= 2) pa1 = __builtin_bit_cast(bf16x8, zu);

    const int off0 = 16 * wh + 8 * g;
    const int off1 = 16 * wh + ((g < 2) ? 32 + 8 * g : 48);
    f32x4 acc[4] = {zero, zero, zero, zero};
#pragma unroll
    for (int dt = 0; dt < 4; ++dt) {
      bf16x8 v0 = *(const bf16x8*)&Vt[(16 * dt + c) * 72 + off0];
      bf16x8 v1 = *(const bf16x8*)&Vt[(16 * dt + c) * 72 + off1];
      acc[dt] = __builtin_amdgcn_mfma_f32_16x16x32_bf16(pa0, v0, acc[dt], 0, 0, 0);
      acc[dt] = __builtin_amdgcn_mfma_f32_16x16x32_bf16(pa1, v1, acc[dt], 0, 0, 0);
    }

#pragma unroll
    for (int dt = 0; dt < 4; ++dt)
#pragma unroll
      for (int r = 0; r < 4; ++r)
        aoutL[(wh * 16 + 4 * g + r) * 520 + h * 64 + 16 * dt + c] = (bf16)acc[dt][r];
  }
  __syncthreads();  // aoutL complete

  // ======== proj phase: BARRIER-FREE; A from LDS, B direct from Bp (L2) ========
  f32x4 acc2[2][4];
#pragma unroll
  for (int m = 0; m < 2; ++m)
#pragma unroll
    for (int n = 0; n < 4; ++n) acc2[m][n] = zero;

#pragma unroll
  for (int t = 0; t < 8; ++t) {
#pragma unroll
    for (int kk = 0; kk < 2; ++kk) {
      const int chunk = t * 8 + kk * 4 + g;
      bf16x8 af[2], bfv[4];
#pragma unroll
      for (int m = 0; m < 2; ++m)
        af[m] = *(const bf16x8*)&aoutL[(m * 16 + c) * 520 + chunk * 8];
#pragma unroll
      for (int n = 0; n < 4; ++n)
        bfv[n] = *(const bf16x8*)(Bp + ((size_t)chunk * 512 + w * 64 + n * 16 + c) * 8);
#pragma unroll
      for (int m = 0; m < 2; ++m)
#pragma unroll
        for (int n = 0; n < 4; ++n)
          acc2[m][n] = __builtin_amdgcn_mfma_f32_16x16x32_bf16(af[m], bfv[n], acc2[m][n], 0, 0, 0);
    }
  }

  const int col0 = w * 64 + c;
  float ps[2][4], ps2[2][4];
#pragma unroll
  for (int m = 0; m < 2; ++m)
#pragma unroll
    for (int r = 0; r < 4; ++r) {
      int row = m0 + m * 16 + 4 * g + r;
      float s = 0.f, s2 = 0.f;
#pragma unroll
      for (int n = 0; n < 4; ++n) {
        float y = acc2[m][n][r] + X[(size_t)row * 512 + col0 + n * 16];
        acc2[m][n][r] = y;
        s += y;
        s2 += y * y;
      }
      ps[m][r] = s;
      ps2[m][r] = s2;
    }
#pragma unroll
  for (int m = 0; m < 2; ++m)
#pragma unroll
    for (int r = 0; r < 4; ++r) {
      float s = ps[m][r], s2 = ps2[m][r];
      s += __shfl_xor(s, 1);  s2 += __shfl_xor(s2, 1);
      s += __shfl_xor(s, 2);  s2 += __shfl_xor(s2, 2);
      s += __shfl_xor(s, 4);  s2 += __shfl_xor(s2, 4);
      s += __shfl_xor(s, 8);  s2 += __shfl_xor(s2, 8);
      ps[m][r] = s;
      ps2[m][r] = s2;
    }
  if (c == 0) {
#pragma unroll
    for (int m = 0; m < 2; ++m)
#pragma unroll
      for (int r = 0; r < 4; ++r) {
        rsum[(m * 16 + 4 * g + r) * 8 + w] = ps[m][r];
        rsq[(m * 16 + 4 * g + r) * 8 + w] = ps2[m][r];
      }
  }
  __syncthreads();

  float gam[4], bet[4];
#pragma unroll
  for (int n = 0; n < 4; ++n) {
    gam[n] = gamma[col0 + n * 16];
    bet[n] = beta[col0 + n * 16];
  }
#pragma unroll
  for (int m = 0; m < 2; ++m)
#pragma unroll
    for (int r = 0; r < 4; ++r) {
      int rl = m * 16 + 4 * g + r;
      float sum = 0.f, sq = 0.f;
#pragma unroll
      for (int j = 0; j < 8; ++j) {
        sum += rsum[rl * 8 + j];
        sq += rsq[rl * 8 + j];
      }
      float mu = sum * (1.f / 512.f);
      float var = sq * (1.f / 512.f) - mu * mu;
      float rs = rsqrtf(var + 1e-5f);
#pragma unroll
      for (int n = 0; n < 4; ++n)
        out[(size_t)(m0 + rl) * 512 + col0 + n * 16] =
            gam[n] * (acc2[m][n][r] - mu) * rs + bet[n];
    }
}

extern "C" void kernel_launch(void* const* d_in, const int* in_sizes, int n_in,
                              void* d_out, int out_size, void* d_ws, size_t ws_size,
                              hipStream_t stream) {
  const float* x  = (const float*)d_in[0];
  const float* Wq = (const float*)d_in[1];
  const float* Wk = (const float*)d_in[2];
  const float* Wv = (const float*)d_in[3];
  const float* Wp = (const float*)d_in[4];
  const float* g  = (const float*)d_in[5];
  const float* be = (const float*)d_in[6];
  float* out = (float*)d_out;

  char* ws = (char*)d_ws;
  bf16* xb   = (bf16*)(ws);                          // 8,388,608 B
  bf16* wqkv = (bf16*)(ws + 8388608);                // 1,572,864 B
  bf16* wpb  = (bf16*)(ws + 9961472);                //   524,288 B (chunk-major)
  bf16* qkv  = (bf16*)(ws + 10485760);               // 25,165,824 B

  prep_kernel<<<2560, 256, 0, stream>>>(x, Wq, Wk, Wv, Wp, xb, wqkv, wpb);
  // QKV: M=8192 (64 tiles of 128), N=1536 (24 tiles of 64) -> 1536 blocks
  gemm_qkv_kernel<<<1536, 256, 0, stream>>>(xb, wqkv, qkv);
  // fused attn + proj + residual + LN: 8192/32 = 256 blocks
  attn_proj_ln_kernel<<<256, 512, 0, stream>>>(qkv, wpb, x, g, be, out);
}